// Round 12
// baseline (70.985 us; speedup 1.0000x reference)
//
#include <hip/hip_runtime.h>
#include <hip/hip_fp16.h>

typedef float f32x4 __attribute__((ext_vector_type(4)));

#define N_SAMPLES 64
#define M_ELEMS   307200              // 480*640 per-sample elements
#define M4        76800               // float4 per sample
#define BLOCK     256
#define BPS       20                  // blocks per sample
#define TPS       (BPS * BLOCK)       // 5120 threads per sample
#define ITERS     15                  // M4/TPS float4 per thread, exact
#define NBLOCKS   (BPS * N_SAMPLES)   // 1280 = 5 blocks/CU on 256 CUs
#define NUM_CU    256
#define SCALE     (1.0f / ((float)M_ELEMS * (float)N_SAMPLES))

// One pred+targ pair of 16B loads sharing a voffset, then advance by
// TPS*16B = 0x14000. sc0+sc1+nt = maximal-scope / no-allocate encoding
// (the one untested bit after R9/R11's sc0+nt null). If this suppresses
// MALL service, every replay is a full-miss CONTIGUOUS stream at ~6.3TB/s
// instead of the hash-scattered half-miss stream at 1.45TB/s.
#define GLOAD2(Ai, Bi)                                                \
    "global_load_dwordx4 %[" #Ai "], %[off], %[PB] sc0 sc1 nt\n\t"    \
    "global_load_dwordx4 %[" #Bi "], %[off], %[TB] sc0 sc1 nt\n\t"    \
    "v_add_u32 %[off], 0x14000, %[off]\n\t"

__device__ __forceinline__ float wave_reduce_max(float v) {
    #pragma unroll
    for (int off = 32; off > 0; off >>= 1)
        v = fmaxf(v, __shfl_down(v, off, 64));
    return v;
}
__device__ __forceinline__ float wave_reduce_sum(float v) {
    #pragma unroll
    for (int off = 32; off > 0; off >>= 1)
        v += __shfl_down(v, off, 64);
    return v;
}

// Fused single-read kernel (R4/R11 structure, proven correct): ONE 157MB
// read per replay, |d| held as packed fp16 in 30 VGPRs, per-sample
// device-scope sync, BerHu from registers. Only change vs R11: sc1 flag.
__global__ __launch_bounds__(BLOCK, 5) void berhu_fused(
        const float* __restrict__ pred,
        const float* __restrict__ targ,
        unsigned int* __restrict__ maxbits,
        unsigned int* __restrict__ done,
        float* __restrict__ out) {
    const int n = blockIdx.y;
    const float* p = pred + (size_t)n * M_ELEMS;
    const float* t = targ + (size_t)n * M_ELEMS;
    unsigned int voff = (unsigned int)((blockIdx.x * BLOCK + threadIdx.x) * 16);

    unsigned int adp[2 * ITERS];      // 30 VGPRs of packed half2 |d|
    float m = 0.0f;
    f32x4 a0, a1, a2, a3, a4, b0, b1, b2, b3, b4;

    // 3 groups of 5 pred/targ pairs: issue 10 loads, drain, convert.
    #define CONSUME(J, AJ, BJ, BASE)                                           \
        {                                                                      \
            float ad0 = fabsf(AJ[0] - BJ[0]);                                  \
            float ad1 = fabsf(AJ[1] - BJ[1]);                                  \
            float ad2 = fabsf(AJ[2] - BJ[2]);                                  \
            float ad3 = fabsf(AJ[3] - BJ[3]);                                  \
            m = fmaxf(m, fmaxf(fmaxf(ad0, ad1), fmaxf(ad2, ad3)));             \
            adp[BASE]     = __builtin_bit_cast(unsigned int,                   \
                                               __floats2half2_rn(ad0, ad1));   \
            adp[BASE + 1] = __builtin_bit_cast(unsigned int,                   \
                                               __floats2half2_rn(ad2, ad3));   \
        }

    #define GROUP(BASE)                                                        \
        asm volatile(                                                          \
            GLOAD2(A0, B0) GLOAD2(A1, B1) GLOAD2(A2, B2)                       \
            GLOAD2(A3, B3) GLOAD2(A4, B4)                                      \
            "s_waitcnt vmcnt(0)\n\t"                                           \
            : [A0]"=&v"(a0), [A1]"=&v"(a1), [A2]"=&v"(a2),                     \
              [A3]"=&v"(a3), [A4]"=&v"(a4),                                    \
              [B0]"=&v"(b0), [B1]"=&v"(b1), [B2]"=&v"(b2),                     \
              [B3]"=&v"(b3), [B4]"=&v"(b4),                                    \
              [off]"+v"(voff)                                                  \
            : [PB]"s"(p), [TB]"s"(t)                                           \
            : "memory");                                                       \
        CONSUME(0, a0, b0, BASE + 0) CONSUME(1, a1, b1, BASE + 2)              \
        CONSUME(2, a2, b2, BASE + 4) CONSUME(3, a3, b3, BASE + 6)              \
        CONSUME(4, a4, b4, BASE + 8)

    GROUP(0)
    GROUP(10)
    GROUP(20)

    // block-reduce max
    m = wave_reduce_max(m);
    __shared__ float sred[BLOCK / 64];
    __shared__ float sc;
    const int wid  = threadIdx.x >> 6;
    const int lane = threadIdx.x & 63;
    if (lane == 0) sred[wid] = m;
    __syncthreads();
    if (threadIdx.x == 0) {
        float bm = sred[0];
        #pragma unroll
        for (int w = 1; w < BLOCK / 64; ++w) bm = fmaxf(bm, sred[w]);
        atomicMax(&maxbits[n], __float_as_uint(bm));   // |d|>=0: bit cmp == float cmp
        __threadfence();                               // maxbits visible before done++
        atomicAdd(&done[n], 1u);
        // All NBLOCKS co-resident (host-gated) -> no deadlock.
        while (atomicMax(&done[n], 0u) < (unsigned)BPS)
            __builtin_amdgcn_s_sleep(8);
        sc = __uint_as_float(atomicMax(&maxbits[n], 0u)) * 0.2f;  // fresh via RMW
    }
    __syncthreads();

    const float c = sc;
    const float c2 = c * c;
    const float inv2c = (c > 0.0f) ? (0.5f / c) : 0.0f;

    float s = 0.0f;
    #pragma unroll
    for (int k = 0; k < 2 * ITERS; ++k) {
        __half2 h = __builtin_bit_cast(__half2, adp[k]);
        float fx = __low2float(h);
        float fy = __high2float(h);
        s += (fx <= c) ? fx : (fx * fx + c2) * inv2c;
        s += (fy <= c) ? fy : (fy * fy + c2) * inv2c;
    }

    s = wave_reduce_sum(s);
    __syncthreads();                 // sred reuse
    if (lane == 0) sred[wid] = s;
    __syncthreads();
    if (threadIdx.x == 0) {
        float bs = sred[0];
        #pragma unroll
        for (int w = 1; w < BLOCK / 64; ++w) bs += sred[w];
        atomicAdd(out, bs * SCALE);
    }
}

// ---- fallback: proven two-pass (R1 structure) ----
__global__ __launch_bounds__(BLOCK) void fb_max(
        const float* __restrict__ pred, const float* __restrict__ targ,
        unsigned int* __restrict__ maxbits) {
    const int n = blockIdx.y;
    const f32x4* p = (const f32x4*)(pred + (size_t)n * M_ELEMS);
    const f32x4* t = (const f32x4*)(targ + (size_t)n * M_ELEMS);
    float m = 0.0f;
    for (int i = blockIdx.x * BLOCK + threadIdx.x; i < M4; i += TPS) {
        f32x4 a = p[i], b = t[i];
        m = fmaxf(m, fmaxf(fmaxf(fabsf(a[0]-b[0]), fabsf(a[1]-b[1])),
                           fmaxf(fabsf(a[2]-b[2]), fabsf(a[3]-b[3]))));
    }
    m = wave_reduce_max(m);
    __shared__ float smax[BLOCK / 64];
    if ((threadIdx.x & 63) == 0) smax[threadIdx.x >> 6] = m;
    __syncthreads();
    if (threadIdx.x == 0) {
        float bm = smax[0];
        for (int w = 1; w < BLOCK / 64; ++w) bm = fmaxf(bm, smax[w]);
        atomicMax(&maxbits[n], __float_as_uint(bm));
    }
}
__global__ __launch_bounds__(BLOCK) void fb_sum(
        const float* __restrict__ pred, const float* __restrict__ targ,
        const unsigned int* __restrict__ maxbits, float* __restrict__ out) {
    const int n = blockIdx.y;
    const float c = __uint_as_float(maxbits[n]) * 0.2f;
    const float c2 = c * c;
    const float inv2c = (c > 0.0f) ? (0.5f / c) : 0.0f;
    const f32x4* p = (const f32x4*)(pred + (size_t)n * M_ELEMS);
    const f32x4* t = (const f32x4*)(targ + (size_t)n * M_ELEMS);
    float s = 0.0f;
    for (int i = blockIdx.x * BLOCK + threadIdx.x; i < M4; i += TPS) {
        f32x4 a = p[i], b = t[i];
        #pragma unroll
        for (int q = 0; q < 4; ++q) {
            float d = a[q] - b[q], ad = fabsf(d);
            s += (ad <= c) ? ad : (d * d + c2) * inv2c;
        }
    }
    s = wave_reduce_sum(s);
    __shared__ float ssum[BLOCK / 64];
    if ((threadIdx.x & 63) == 0) ssum[threadIdx.x >> 6] = s;
    __syncthreads();
    if (threadIdx.x == 0) {
        float bs = ssum[0];
        for (int w = 1; w < BLOCK / 64; ++w) bs += ssum[w];
        atomicAdd(out, bs * SCALE);
    }
}

extern "C" void kernel_launch(void* const* d_in, const int* in_sizes, int n_in,
                              void* d_out, int out_size, void* d_ws, size_t ws_size,
                              hipStream_t stream) {
    const float* pred = (const float*)d_in[0];
    const float* targ = (const float*)d_in[1];
    float* out = (float*)d_out;

    unsigned int* maxbits = (unsigned int*)d_ws;              // [64]
    unsigned int* done    = (unsigned int*)d_ws + N_SAMPLES;  // [64]

    // ws/out poisoned 0xAA, not re-poisoned between replays — zero every call.
    hipMemsetAsync(d_ws, 0, 2 * N_SAMPLES * sizeof(unsigned int), stream);
    hipMemsetAsync(d_out, 0, sizeof(float), stream);

    // Residency gate for the spin-sync (deterministic host query, capture-safe).
    int nb = 0;
    hipError_t qe = hipOccupancyMaxActiveBlocksPerMultiprocessor(
        &nb, (const void*)berhu_fused, BLOCK, 0);
    const bool coop_ok = (qe == hipSuccess) && (nb * NUM_CU >= NBLOCKS);

    dim3 grid(BPS, N_SAMPLES);
    if (coop_ok) {
        berhu_fused<<<grid, BLOCK, 0, stream>>>(pred, targ, maxbits, done, out);
    } else {
        fb_max<<<grid, BLOCK, 0, stream>>>(pred, targ, maxbits);
        fb_sum<<<grid, BLOCK, 0, stream>>>(pred, targ, maxbits, out);
    }
}

// Round 13
// 69.743 us; speedup vs baseline: 1.0178x; 1.0178x over previous
//
#include <hip/hip_runtime.h>

typedef float f32x4 __attribute__((ext_vector_type(4)));

#define N_SAMPLES 64
#define M_ELEMS   307200            // 480*640 per-sample elements
#define M4        76800             // float4 per sample
#define BLOCK     256
#define BPS       25                // blocks per sample
#define TPS       (BPS * BLOCK)     // 6400 threads per sample
#define ITERS     12                // M4 / TPS exactly
#define SCALE     (1.0f / ((float)M_ELEMS * (float)N_SAMPLES))

__device__ __forceinline__ float wave_reduce_max(float v) {
    #pragma unroll
    for (int off = 32; off > 0; off >>= 1)
        v = fmaxf(v, __shfl_down(v, off, 64));
    return v;
}
__device__ __forceinline__ float wave_reduce_sum(float v) {
    #pragma unroll
    for (int off = 32; off > 0; off >>= 1)
        v += __shfl_down(v, off, 64);
    return v;
}

// Pass 1: per-sample max of |pred-targ| — FORWARD sweep (low addr -> high).
__global__ __launch_bounds__(BLOCK) void berhu_max_kernel(
        const float* __restrict__ pred,
        const float* __restrict__ targ,
        unsigned int* __restrict__ maxbits) {
    const int n = blockIdx.y;
    const f32x4* p = (const f32x4*)(pred + (size_t)n * M_ELEMS);
    const f32x4* t = (const f32x4*)(targ + (size_t)n * M_ELEMS);

    float m = 0.0f;
    int i = blockIdx.x * BLOCK + threadIdx.x;
    #pragma unroll
    for (int k = 0; k < ITERS; ++k, i += TPS) {
        f32x4 a = p[i];
        f32x4 b = t[i];
        float m0 = fmaxf(fabsf(a[0] - b[0]), fabsf(a[1] - b[1]));
        float m1 = fmaxf(fabsf(a[2] - b[2]), fabsf(a[3] - b[3]));
        m = fmaxf(m, fmaxf(m0, m1));
    }

    m = wave_reduce_max(m);
    __shared__ float smax[BLOCK / 64];
    const int wid  = threadIdx.x >> 6;
    const int lane = threadIdx.x & 63;
    if (lane == 0) smax[wid] = m;
    __syncthreads();
    if (threadIdx.x == 0) {
        float bm = smax[0];
        #pragma unroll
        for (int w = 1; w < BLOCK / 64; ++w) bm = fmaxf(bm, smax[w]);
        atomicMax(&maxbits[n], __float_as_uint(bm));   // |d|>=0: bit cmp == float cmp
    }
}

// Pass 2: BerHu sum — BACKWARD sweep (high addr -> low). Serpentine traversal:
// starts where pass 1 just finished (MALL-resident tail), takes its misses as
// one contiguous low-address chunk at burst rate instead of a hash-scattered
// 50% pattern. Next replay's forward max pass then starts at address 0, which
// this pass just made resident.
__global__ __launch_bounds__(BLOCK) void berhu_sum_kernel(
        const float* __restrict__ pred,
        const float* __restrict__ targ,
        const unsigned int* __restrict__ maxbits,
        float* __restrict__ out) {
    const int n  = (N_SAMPLES - 1) - blockIdx.y;          // reversed sample order
    const int bx = (BPS - 1) - blockIdx.x;                // reversed block order
    const float c = __uint_as_float(maxbits[n]) * 0.2f;   // max/5
    const float c2 = c * c;
    const float inv2c = (c > 0.0f) ? (0.5f / c) : 0.0f;

    const f32x4* p = (const f32x4*)(pred + (size_t)n * M_ELEMS);
    const f32x4* t = (const f32x4*)(targ + (size_t)n * M_ELEMS);
    const int i0 = bx * BLOCK + threadIdx.x;

    float s = 0.0f;
    #pragma unroll
    for (int k = ITERS - 1; k >= 0; --k) {                // reversed k order
        const int i = i0 + k * TPS;
        f32x4 a = p[i];
        f32x4 b = t[i];
        #pragma unroll
        for (int q = 0; q < 4; ++q) {
            float d = a[q] - b[q], ad = fabsf(d);
            s += (ad <= c) ? ad : (d * d + c2) * inv2c;
        }
    }

    s = wave_reduce_sum(s);
    __shared__ float ssum[BLOCK / 64];
    const int wid  = threadIdx.x >> 6;
    const int lane = threadIdx.x & 63;
    if (lane == 0) ssum[wid] = s;
    __syncthreads();
    if (threadIdx.x == 0) {
        float bs = ssum[0];
        #pragma unroll
        for (int w = 1; w < BLOCK / 64; ++w) bs += ssum[w];
        atomicAdd(out, bs * SCALE);
    }
}

extern "C" void kernel_launch(void* const* d_in, const int* in_sizes, int n_in,
                              void* d_out, int out_size, void* d_ws, size_t ws_size,
                              hipStream_t stream) {
    const float* pred = (const float*)d_in[0];
    const float* targ = (const float*)d_in[1];
    float* out = (float*)d_out;

    unsigned int* maxbits = (unsigned int*)d_ws;

    // ws/out poisoned 0xAA, not re-poisoned between replays — zero every call.
    hipMemsetAsync(d_ws, 0, N_SAMPLES * sizeof(unsigned int), stream);
    hipMemsetAsync(d_out, 0, sizeof(float), stream);

    dim3 grid(BPS, N_SAMPLES);
    berhu_max_kernel<<<grid, BLOCK, 0, stream>>>(pred, targ, maxbits);
    berhu_sum_kernel<<<grid, BLOCK, 0, stream>>>(pred, targ, maxbits, out);
}